// Round 8
// baseline (976.650 us; speedup 1.0000x reference)
//
#include <hip/hip_runtime.h>
#include <math.h>
#include <stdint.h>

// Problem constants (fixed by setup_inputs)
#define M     4096      // source rows
#define NTGT  65536     // target rows
#define KD    1024      // feature dim

// Screen tiling: 128x128 tile, 4 waves, BK=32, 3-deep counted-vmcnt pipeline
#define NS    32            // target slices
#define SLICE (NTGT / NS)   // 2048 targets per block
#define BT    128           // targets per tile
#define BS    128           // sources per block
#define NTILE (SLICE / BT)  // 16 target tiles per block
#define TSTEP 32            // K-steps per tile (KD/32)
#define TOTST (NTILE * TSTEP) // 512 K-steps per block
#define NCAND 256           // candidates per source row (NS * 8)
#define BUFSZ 16384         // one K-step buffer (A 8KB | B 8KB)

typedef __attribute__((ext_vector_type(8))) short bf16x8;   // 4 VGPRs of bf16
typedef __attribute__((ext_vector_type(4))) float f32x4;

// ---------------------------------------------------------------------------
// helpers
// ---------------------------------------------------------------------------
__device__ __forceinline__ ushort f2bf(float f) {
    uint32_t u = __float_as_uint(f);
    uint32_t r = (u + 0x7FFFu + ((u >> 16) & 1u)) >> 16;   // RNE; no NaN inputs
    return (ushort)r;
}

template <int NK>
__device__ __forceinline__ void insert_desc(uint32_t (&arr)[NK], uint32_t pk) {
    uint32_t cur = pk;
#pragma unroll
    for (int s = 0; s < NK; ++s) {
        uint32_t old = arr[s];
        bool g = __uint_as_float(cur) > __uint_as_float(old);
        arr[s] = g ? cur : old;
        cur    = g ? old : cur;
    }
}

__device__ __forceinline__ void gload16(const void* g, void* l) {
    __builtin_amdgcn_global_load_lds(
        (const __attribute__((address_space(1))) unsigned int*)g,
        (__attribute__((address_space(3))) unsigned int*)l, 16, 0, 0);
}

// ---------------------------------------------------------------------------
// Prep A: per-target inverse norm + normalized bf16 target copy
// ---------------------------------------------------------------------------
__global__ void prep_targets(const float* __restrict__ T, float* __restrict__ tinv,
                             ushort* __restrict__ Tb) {
    const int wave = threadIdx.x >> 6;
    const int lane = threadIdx.x & 63;
    const int row  = blockIdx.x * 4 + wave;
    const float* p = T + (size_t)row * KD;
    float4 v[4];
    float s = 0.f;
#pragma unroll
    for (int j = 0; j < 4; ++j) {
        v[j] = *reinterpret_cast<const float4*>(p + lane * 4 + j * 256);
        s += v[j].x * v[j].x + v[j].y * v[j].y + v[j].z * v[j].z + v[j].w * v[j].w;
    }
#pragma unroll
    for (int off = 32; off; off >>= 1) s += __shfl_xor(s, off);
    const float rinv = 1.0f / sqrtf(fmaxf(s, 1e-24f));
    if (lane == 0) tinv[row] = rinv;
#pragma unroll
    for (int j = 0; j < 4; ++j) {
        ushort4 o;
        o.x = f2bf(v[j].x * rinv); o.y = f2bf(v[j].y * rinv);
        o.z = f2bf(v[j].z * rinv); o.w = f2bf(v[j].w * rinv);
        *reinterpret_cast<ushort4*>(Tb + (size_t)row * KD + lane * 4 + j * 256) = o;
    }
}

// Prep B: raw bf16 source copy (source norm does not affect per-row ranking)
__global__ void prep_source(const float* __restrict__ S, ushort* __restrict__ Sb) {
    const int wave = threadIdx.x >> 6;
    const int lane = threadIdx.x & 63;
    const int row  = blockIdx.x * 4 + wave;
    const float* p = S + (size_t)row * KD;
#pragma unroll
    for (int j = 0; j < 4; ++j) {
        float4 v = *reinterpret_cast<const float4*>(p + lane * 4 + j * 256);
        ushort4 o;
        o.x = f2bf(v.x); o.y = f2bf(v.y); o.z = f2bf(v.z); o.w = f2bf(v.w);
        *reinterpret_cast<ushort4*>(Sb + (size_t)row * KD + lane * 4 + j * 256) = o;
    }
}

// ---------------------------------------------------------------------------
// Screen: 128x128 bf16 MFMA GEMM + per-lane packed top-8 per source column.
// 256 threads = 4 waves (2 target halves x 2 source halves). 3-deep pipeline:
//   STAGE(s+2) -> s_waitcnt vmcnt(8) -> s_barrier -> 8 ds_read_b128 ->
//   16 MFMA -> s_barrier            (tail: vmcnt 8 -> 4 -> 0)
// 3x16KB LDS buffers (A 8KB | B 8KB each), s%3 indexed; 48KB -> 3 blocks/CU.
// Beat-conflict-free read swizzle: chunk16 ^= (row>>1)&3 (write side via
// pre-swizzled global source, read side compile-time lane offset).
// Grid (bx fastest): same-slice blocks dispatch back-to-back -> L2/L3
// temporal reuse of the 4MB A-slice (R3-measured best fetch).
// ---------------------------------------------------------------------------
__global__ __launch_bounds__(256, 3)
void screen_kernel(const ushort* __restrict__ Sb, const ushort* __restrict__ Tb,
                   uint32_t* __restrict__ cand_out) {
    __shared__ __align__(16) unsigned char lds[3 * BUFSZ];

    const int tid  = threadIdx.x;
    const int lane = tid & 63, wid = tid >> 6;
    const int wr = wid >> 1, wc = wid & 1;
    const int l15 = lane & 15, l4 = lane >> 4;

    const int bx = blockIdx.x;           // source block (fastest -> co-dispatch)
    const int by = blockIdx.y;           // target slice
    const int sb   = bx * BS;
    const int tgt0 = by * SLICE;

    // staging: thread covers one 16B chunk of one 64B row; pre-swizzled source
    // (physical chunk p=tid&3 holds logical chunk p ^ ((row>>1)&3), row=tid>>2)
    const int srow = tid >> 2;                           // 0..63
    const int scc  = ((tid & 3) ^ ((tid >> 3) & 3)) * 8; // logical elem offset
    const ushort* aStage = Tb + (size_t)(tgt0 + srow) * KD + scc;
    const ushort* bStage = Sb + (size_t)(sb   + srow) * KD + scc;

    // fragment read: physical chunk = l4 ^ ((row>>1)&3), row ≡ l15 (mod 16)
    const int swz = (l4 ^ ((l15 >> 1) & 3)) * 16;
    int aOff[4], bOff[4];
#pragma unroll
    for (int mg = 0; mg < 4; ++mg) aOff[mg] = (wr * 64 + mg * 16 + l15) * 64 + swz;
#pragma unroll
    for (int ng = 0; ng < 4; ++ng) bOff[ng] = 8192 + (wc * 64 + ng * 16 + l15) * 64 + swz;

#define BARX()  __builtin_amdgcn_s_barrier()
#define FENCE() asm volatile("" ::: "memory")
#define VM8()   asm volatile("s_waitcnt vmcnt(8)" ::: "memory")
#define VM4()   asm volatile("s_waitcnt vmcnt(4)" ::: "memory")
#define VM0()   asm volatile("s_waitcnt vmcnt(0)" ::: "memory")

    // STAGE(s): 4 gloads (A rows 0-63, A rows 64-127, B rows 0-63, B rows 64-127)
#define STAGE(s_) do {                                                         \
        const int tt_ = (s_) >> 5, ks_ = (s_) & 31;                            \
        unsigned char* d_ = lds + ((uint32_t)(s_) % 3u) * BUFSZ + tid * 16;    \
        const ushort* a_ = aStage + (size_t)(tt_ * BT) * KD + ks_ * 32;        \
        const ushort* b_ = bStage + ks_ * 32;                                  \
        gload16(a_,           d_);                                             \
        gload16(a_ + 64 * KD, d_ + 4096);                                      \
        gload16(b_,           d_ + 8192);                                      \
        gload16(b_ + 64 * KD, d_ + 8192 + 4096);                               \
    } while (0)

    uint32_t cand[4][8];
#pragma unroll
    for (int n = 0; n < 4; ++n)
#pragma unroll
        for (int j = 0; j < 8; ++j) cand[n][j] = 0xFF800000u;   // -inf, idx 0

    STAGE(0);
    STAGE(1);

#pragma unroll 1
    for (int tt = 0; tt < NTILE; ++tt) {
        f32x4 acc[4][4];
#pragma unroll
        for (int mg = 0; mg < 4; ++mg)
#pragma unroll
            for (int ng = 0; ng < 4; ++ng) acc[mg][ng] = (f32x4){0.f, 0.f, 0.f, 0.f};

#pragma unroll 1
        for (int ks = 0; ks < TSTEP; ++ks) {
            const int s = tt * TSTEP + ks;
            if (s + 2 < TOTST)      { STAGE(s + 2); VM8(); }
            else if (s + 1 < TOTST) { VM4(); }
            else                    { VM0(); }
            BARX(); FENCE();

            const unsigned char* cb = lds + ((uint32_t)s % 3u) * BUFSZ;
            bf16x8 af[4], bf[4];
#pragma unroll
            for (int mg = 0; mg < 4; ++mg)
                af[mg] = *reinterpret_cast<const bf16x8*>(cb + aOff[mg]);
#pragma unroll
            for (int ng = 0; ng < 4; ++ng)
                bf[ng] = *reinterpret_cast<const bf16x8*>(cb + bOff[ng]);
#pragma unroll
            for (int mg = 0; mg < 4; ++mg)
#pragma unroll
                for (int ng = 0; ng < 4; ++ng)
                    acc[mg][ng] = __builtin_amdgcn_mfma_f32_16x16x32_bf16(af[mg], bf[ng], acc[mg][ng], 0, 0, 0);

            FENCE(); BARX();
        }

        // screening scan (registers only; in-flight stages keep flying)
        // C layout: col=l15 (source), row = l4*4+q (target within fragment)
        const int tb = tgt0 + tt * BT;
#pragma unroll
        for (int n = 0; n < 4; ++n) {
            float c7 = __uint_as_float(cand[n][7]);
#pragma unroll
            for (int mg = 0; mg < 4; ++mg) {
#pragma unroll
                for (int q = 0; q < 4; ++q) {
                    const float v = acc[mg][n][q];
                    if (v > c7) {
                        const int tg = tb + wr * 64 + mg * 16 + l4 * 4 + q;
                        const uint32_t pk = (__float_as_uint(v) & 0xFFFF0000u) | (uint32_t)tg;
                        insert_desc<8>(cand[n], pk);
                        c7 = __uint_as_float(cand[n][7]);
                    }
                }
            }
        }
    }
#undef STAGE

    // ---- candidate merge ----
    // intra-wave: 4 owner lanes per source column (l4=0..3) -> lane l4=0
#pragma unroll
    for (int n = 0; n < 4; ++n) {
#pragma unroll
        for (int off = 32; off >= 16; off >>= 1) {
            uint32_t inc[8];
#pragma unroll
            for (int j = 0; j < 8; ++j)
                inc[j] = (uint32_t)__shfl_down((int)cand[n][j], off);
#pragma unroll
            for (int j = 0; j < 8; ++j)
                if (__uint_as_float(inc[j]) > __uint_as_float(cand[n][7]))
                    insert_desc<8>(cand[n], inc[j]);
        }
    }

    __syncthreads();                     // full drain; LDS reusable
    uint32_t* mbuf = (uint32_t*)lds;     // [128 sources][16 slots] = 8KB
    if (l4 == 0) {
#pragma unroll
        for (int n = 0; n < 4; ++n) {
            const int sc = wc * 64 + n * 16 + l15;
#pragma unroll
            for (int j = 0; j < 8; ++j) mbuf[sc * 16 + wr * 8 + j] = cand[n][j];
        }
    }
    __syncthreads();

    if (tid < BS) {
        uint32_t best[8];
#pragma unroll
        for (int j = 0; j < 8; ++j) best[j] = 0xFF800000u;
        const uint32_t* rowp = mbuf + tid * 16;
#pragma unroll
        for (int c = 0; c < 16; ++c) {
            const uint32_t pk = rowp[c];
            if (__uint_as_float(pk) > __uint_as_float(best[7])) insert_desc<8>(best, pk);
        }
        uint32_t* dst = cand_out + (size_t)(sb + tid) * NCAND + by * 8;
#pragma unroll
        for (int j = 0; j < 8; ++j) dst[j] = best[j];
    }
}

// ---------------------------------------------------------------------------
// Final: per source row, screen-top-16 of NCAND candidates -> fp32 rescore ->
// exact top-4 -> gather + mean. One block (256 threads) per row.
// ---------------------------------------------------------------------------
__global__ __launch_bounds__(256)
void final_kernel(const uint32_t* __restrict__ cand_out, const float* __restrict__ S,
                  const float* __restrict__ T, const float* __restrict__ tinv,
                  float* __restrict__ out) {
    __shared__ uint32_t cl[NCAND];
    __shared__ __align__(16) float srow[KD];
    __shared__ float rv[16];
    __shared__ int   ri[16];
    __shared__ int   sel[4];

    const int r = blockIdx.x;
    const int tid = threadIdx.x;

    cl[tid] = cand_out[(size_t)r * NCAND + tid];
    *reinterpret_cast<float4*>(srow + tid * 4) =
        *reinterpret_cast<const float4*>(S + (size_t)r * KD + tid * 4);
    __syncthreads();

    if (tid == 0) {
        uint32_t best[16];
#pragma unroll
        for (int j = 0; j < 16; ++j) best[j] = 0xFF800000u;
        for (int c = 0; c < NCAND; ++c) {
            const uint32_t pk = cl[c];
            if (__uint_as_float(pk) > __uint_as_float(best[15])) insert_desc<16>(best, pk);
        }
#pragma unroll
        for (int j = 0; j < 16; ++j) ri[j] = (int)(best[j] & 0xFFFFu);
    }
    __syncthreads();

    const int lane = tid & 63, wv = tid >> 6;
    for (int c = wv; c < 16; c += 4) {
        const int idx = ri[c];
        const float* tp = T + (size_t)idx * KD;
        float s = 0.f;
#pragma unroll
        for (int j = 0; j < 4; ++j) {
            const float4 tv = *reinterpret_cast<const float4*>(tp + lane * 4 + j * 256);
            const float4 sv = *reinterpret_cast<const float4*>(srow + lane * 4 + j * 256);
            s += tv.x * sv.x + tv.y * sv.y + tv.z * sv.z + tv.w * sv.w;
        }
#pragma unroll
        for (int off = 32; off; off >>= 1) s += __shfl_xor(s, off);
        if (lane == 0) rv[c] = s * tinv[idx];
    }
    __syncthreads();

    if (tid == 0) {
        float b0 = -INFINITY, b1 = -INFINITY, b2 = -INFINITY, b3 = -INFINITY;
        int s0 = 0, s1 = 0, s2 = 0, s3 = 0;
        for (int c = 0; c < 16; ++c) {
            const float v = rv[c]; const int id = ri[c];
            if (v > b3) {
                if (v > b0)      { b3=b2;s3=s2; b2=b1;s2=s1; b1=b0;s1=s0; b0=v;s0=id; }
                else if (v > b1) { b3=b2;s3=s2; b2=b1;s2=s1; b1=v;s1=id; }
                else if (v > b2) { b3=b2;s3=s2; b2=v;s2=id; }
                else             { b3=v;s3=id; }
            }
        }
        sel[0]=s0; sel[1]=s1; sel[2]=s2; sel[3]=s3;
    }
    __syncthreads();

    float4 a = make_float4(0.f, 0.f, 0.f, 0.f);
#pragma unroll
    for (int q = 0; q < 4; ++q) {
        const float4 v = *reinterpret_cast<const float4*>(T + (size_t)sel[q] * KD + tid * 4);
        a.x += v.x; a.y += v.y; a.z += v.z; a.w += v.w;
    }
    a.x *= 0.25f; a.y *= 0.25f; a.z *= 0.25f; a.w *= 0.25f;
    *reinterpret_cast<float4*>(out + (size_t)r * KD + tid * 4) = a;
}

// ===========================================================================
// Fallback (round-1 proven fp32 path) — used only if ws_size is too small.
// ===========================================================================
#define FNS    32
#define FSLICE (NTGT / FNS)
#define FBM 128
#define FBN 128
#define FBK 16
#define FNTILE (FSLICE / FBN)
#define FLDA 132
#define FLDSS 33

__global__ void tinv_kernel(const float* __restrict__ T, float* __restrict__ tinv) {
    const int wave = threadIdx.x >> 6;
    const int lane = threadIdx.x & 63;
    const int row  = blockIdx.x * 4 + wave;
    const float* p = T + (size_t)row * KD;
    float s = 0.f;
#pragma unroll
    for (int j = 0; j < 4; ++j) {
        float4 v = *reinterpret_cast<const float4*>(p + lane * 4 + j * 256);
        s += v.x * v.x + v.y * v.y + v.z * v.z + v.w * v.w;
    }
#pragma unroll
    for (int off = 32; off; off >>= 1) s += __shfl_xor(s, off);
    if (lane == 0) tinv[row] = 1.0f / sqrtf(fmaxf(s, 1e-24f));
}

__global__ __launch_bounds__(256, 2)
void simtopk_kernel(const float* __restrict__ S, const float* __restrict__ T,
                    const float* __restrict__ tinv,
                    float* __restrict__ pval, int* __restrict__ pidx) {
    __shared__ float smem[2 * FBK * FLDA];
    __shared__ float tinvS[FBN];
    float* As = smem;
    float* Bs = smem + FBK * FLDA;
    float* Ss = smem;

    const int tid = threadIdx.x;
    const int tx = tid & 15, ty = tid >> 4;
    const int rb   = blockIdx.x;
    const int tgt0 = blockIdx.y * FSLICE;
    const size_t abase = (size_t)(rb * FBM) * KD;

    float t0 = -INFINITY, t1 = -INFINITY, t2 = -INFINITY, t3 = -INFINITY;
    int   i0 = 0, i1 = 0, i2 = 0, i3 = 0;

    for (int nt = 0; nt < FNTILE; ++nt) {
        const int tb = tgt0 + nt * FBN;
        float acc[8][8];
#pragma unroll
        for (int i = 0; i < 8; ++i)
#pragma unroll
            for (int j = 0; j < 8; ++j) acc[i][j] = 0.f;

        for (int kk = 0; kk < KD; kk += FBK) {
            const int rr = tid >> 2;
            const int c4 = (tid & 3) * 4;
#pragma unroll
            for (int h = 0; h < 2; ++h) {
                const int row = rr + h * 64;
                float4 av = *reinterpret_cast<const float4*>(S + abase + (size_t)row * KD + kk + c4);
                float4 bv = *reinterpret_cast<const float4*>(T + (size_t)(tb + row) * KD + kk + c4);
                As[(c4 + 0) * FLDA + row] = av.x; As[(c4 + 1) * FLDA + row] = av.y;
                As[(c4 + 2) * FLDA + row] = av.z; As[(c4 + 3) * FLDA + row] = av.w;
                Bs[(c4 + 0) * FLDA + row] = bv.x; Bs[(c4 + 1) * FLDA + row] = bv.y;
                Bs[(c4 + 2) * FLDA + row] = bv.z; Bs[(c4 + 3) * FLDA + row] = bv.w;
            }
            __syncthreads();
#pragma unroll
            for (int k = 0; k < FBK; ++k) {
                float a[8], b[8];
                *reinterpret_cast<float4*>(&a[0]) = *reinterpret_cast<float4*>(&As[k * FLDA + ty * 8]);
                *reinterpret_cast<float4*>(&a[4]) = *reinterpret_cast<float4*>(&As[k * FLDA + ty * 8 + 4]);
                *reinterpret_cast<float4*>(&b[0]) = *reinterpret_cast<float4*>(&Bs[k * FLDA + tx * 4]);
                *reinterpret_cast<float4*>(&b[4]) = *reinterpret_cast<float4*>(&Bs[k * FLDA + 64 + tx * 4]);
#pragma unroll
                for (int i = 0; i < 8; ++i)
#pragma unroll
                    for (int j = 0; j < 8; ++j)
                        acc[i][j] = fmaf(a[i], b[j], acc[i][j]);
            }
            __syncthreads();
        }

        if (tid < FBN) tinvS[tid] = tinv[tb + tid];
        __syncthreads();

#pragma unroll
        for (int cc = 0; cc < 4; ++cc) {
            const int g = cc >> 1;
            if ((tx >> 3) == (cc & 1)) {
                const int txl = tx & 7;
#pragma unroll
                for (int i = 0; i < 8; ++i) {
                    const int rrow = ty * 8 + i;
#pragma unroll
                    for (int j = 0; j < 4; ++j) {
                        const int colc = 4 * txl + j;
                        Ss[rrow * FLDSS + colc] = acc[i][g * 4 + j] * tinvS[cc * 32 + colc];
                    }
                }
            }
            __syncthreads();
            if (tid < FBM) {
#pragma unroll 4
                for (int c = 0; c < 32; ++c) {
                    const float v = Ss[tid * FLDSS + c];
                    if (v > t3) {
                        const int gi = tb + cc * 32 + c;
                        if (v > t0)      { t3=t2;i3=i2; t2=t1;i2=i1; t1=t0;i1=i0; t0=v;i0=gi; }
                        else if (v > t1) { t3=t2;i3=i2; t2=t1;i2=i1; t1=v;i1=gi; }
                        else if (v > t2) { t3=t2;i3=i2; t2=v;i2=gi; }
                        else             { t3=v;i3=gi; }
                    }
                }
            }
            __syncthreads();
        }
    }

    if (tid < FBM) {
        const int row = rb * FBM + tid;
        const size_t base = ((size_t)blockIdx.y * M + row) * 4;
        pval[base + 0] = t0; pval[base + 1] = t1; pval[base + 2] = t2; pval[base + 3] = t3;
        pidx[base + 0] = i0; pidx[base + 1] = i1; pidx[base + 2] = i2; pidx[base + 3] = i3;
    }
}

__global__ void merge_kernel(const float* __restrict__ pval, const int* __restrict__ pidx,
                             const float* __restrict__ T, float* __restrict__ out) {
    __shared__ float cv[FNS * 4];
    __shared__ int   ci[FNS * 4];
    __shared__ int   sel[4];
    const int r = blockIdx.x;
    const int tid = threadIdx.x;

    if (tid < FNS * 4) {
        const int s = tid >> 2, q = tid & 3;
        const size_t base = ((size_t)s * M + r) * 4 + q;
        cv[tid] = pval[base];
        ci[tid] = pidx[base];
    }
    __syncthreads();

    if (tid == 0) {
        float t0 = -INFINITY, t1 = -INFINITY, t2 = -INFINITY, t3 = -INFINITY;
        int   j0 = 0, j1 = 0, j2 = 0, j3 = 0;
        for (int c = 0; c < FNS * 4; ++c) {
            const float v = cv[c];
            if (v > t3) {
                const int gi = ci[c];
                if (v > t0)      { t3=t2;j3=j2; t2=t1;j2=j1; t1=t0;j1=j0; t0=v;j0=gi; }
                else if (v > t1) { t3=t2;j3=j2; t2=t1;j2=j1; t1=v;j1=gi; }
                else if (v > t2) { t3=t2;j3=j2; t2=v;j2=gi; }
                else             { t3=v;j3=gi; }
            }
        }
        sel[0] = j0; sel[1] = j1; sel[2] = j2; sel[3] = j3;
    }
    __syncthreads();

    const int d = tid * 4;
    float4 a = make_float4(0.f, 0.f, 0.f, 0.f);
#pragma unroll
    for (int q = 0; q < 4; ++q) {
        const float4 v = *reinterpret_cast<const float4*>(T + (size_t)sel[q] * KD + d);
        a.x += v.x; a.y += v.y; a.z += v.z; a.w += v.w;
    }
    a.x *= 0.25f; a.y *= 0.25f; a.z *= 0.25f; a.w *= 0.25f;
    *reinterpret_cast<float4*>(out + (size_t)r * KD + d) = a;
}

// ---------------------------------------------------------------------------
extern "C" void kernel_launch(void* const* d_in, const int* in_sizes, int n_in,
                              void* d_out, int out_size, void* d_ws, size_t ws_size,
                              hipStream_t stream) {
    const float* S = (const float*)d_in[0];   // [4096,1024]
    const float* T = (const float*)d_in[1];   // [65536,1024]
    float* out = (float*)d_out;               // [4096,1024]

    const size_t sz_tinv = (size_t)NTGT * 4;                 // 256 KB
    const size_t sz_Sb   = (size_t)M * KD * 2;               // 8 MB
    const size_t sz_Tb   = (size_t)NTGT * KD * 2;            // 128 MB
    const size_t sz_cand = (size_t)M * NCAND * 4;            // 4 MB
    const size_t need = sz_tinv + sz_Sb + sz_Tb + sz_cand;   // ~140.3 MB

    if (ws_size >= need) {
        float*    tinv = (float*)d_ws;
        ushort*   Sb   = (ushort*)((char*)d_ws + sz_tinv);
        ushort*   Tb   = (ushort*)((char*)d_ws + sz_tinv + sz_Sb);
        uint32_t* cand = (uint32_t*)((char*)d_ws + sz_tinv + sz_Sb + sz_Tb);

        prep_targets<<<NTGT / 4, 256, 0, stream>>>(T, tinv, Tb);
        prep_source<<<M / 4, 256, 0, stream>>>(S, Sb);
        screen_kernel<<<dim3(M / BS, NS), 256, 0, stream>>>(Sb, Tb, cand);
        final_kernel<<<M, 256, 0, stream>>>(cand, S, T, tinv, out);
    } else {
        // round-1 fp32 fallback (~7 ms, proven correct)
        float* tinv = (float*)d_ws;
        float* pval = tinv + NTGT;
        int*   pidx = (int*)(pval + (size_t)FNS * M * 4);

        tinv_kernel<<<NTGT / 4, 256, 0, stream>>>(T, tinv);
        simtopk_kernel<<<dim3(M / FBM, FNS), 256, 0, stream>>>(S, T, tinv, pval, pidx);
        merge_kernel<<<M, 256, 0, stream>>>(pval, pidx, T, out);
    }
}

// Round 9
// 828.853 us; speedup vs baseline: 1.1783x; 1.1783x over previous
//
#include <hip/hip_runtime.h>
#include <math.h>
#include <stdint.h>

// Problem constants (fixed by setup_inputs)
#define M     4096      // source rows
#define NTGT  65536     // target rows
#define KD    1024      // feature dim

// Screen tiling: 256x256 tile, 8 waves, BK=32, 2-buffer 1-ahead pipeline
#define NS    32            // target slices
#define SLICE (NTGT / NS)   // 2048 targets per block
#define BT    256           // targets per tile
#define BS    256           // sources per block
#define NTILE (SLICE / BT)  // 8 target tiles per block
#define TSTEP 32            // K-steps per tile (KD/32)
#define TOTST (NTILE * TSTEP) // 256 K-steps per block
#define NCAND 256           // candidates per source row (NS * 8)
#define BUFSZ 32768         // one K-step buffer (A 16KB | B 16KB)

typedef __attribute__((ext_vector_type(8))) short bf16x8;   // 4 VGPRs of bf16
typedef __attribute__((ext_vector_type(4))) float f32x4;

// ---------------------------------------------------------------------------
// helpers
// ---------------------------------------------------------------------------
__device__ __forceinline__ ushort f2bf(float f) {
    uint32_t u = __float_as_uint(f);
    uint32_t r = (u + 0x7FFFu + ((u >> 16) & 1u)) >> 16;   // RNE; no NaN inputs
    return (ushort)r;
}

template <int NK>
__device__ __forceinline__ void insert_desc(uint32_t (&arr)[NK], uint32_t pk) {
    uint32_t cur = pk;
#pragma unroll
    for (int s = 0; s < NK; ++s) {
        uint32_t old = arr[s];
        bool g = __uint_as_float(cur) > __uint_as_float(old);
        arr[s] = g ? cur : old;
        cur    = g ? old : cur;
    }
}

__device__ __forceinline__ void gload16(const void* g, void* l) {
    __builtin_amdgcn_global_load_lds(
        (const __attribute__((address_space(1))) unsigned int*)g,
        (__attribute__((address_space(3))) unsigned int*)l, 16, 0, 0);
}

// ---------------------------------------------------------------------------
// Prep A: per-target inverse norm + normalized bf16 target copy
// ---------------------------------------------------------------------------
__global__ void prep_targets(const float* __restrict__ T, float* __restrict__ tinv,
                             ushort* __restrict__ Tb) {
    const int wave = threadIdx.x >> 6;
    const int lane = threadIdx.x & 63;
    const int row  = blockIdx.x * 4 + wave;
    const float* p = T + (size_t)row * KD;
    float4 v[4];
    float s = 0.f;
#pragma unroll
    for (int j = 0; j < 4; ++j) {
        v[j] = *reinterpret_cast<const float4*>(p + lane * 4 + j * 256);
        s += v[j].x * v[j].x + v[j].y * v[j].y + v[j].z * v[j].z + v[j].w * v[j].w;
    }
#pragma unroll
    for (int off = 32; off; off >>= 1) s += __shfl_xor(s, off);
    const float rinv = 1.0f / sqrtf(fmaxf(s, 1e-24f));
    if (lane == 0) tinv[row] = rinv;
#pragma unroll
    for (int j = 0; j < 4; ++j) {
        ushort4 o;
        o.x = f2bf(v[j].x * rinv); o.y = f2bf(v[j].y * rinv);
        o.z = f2bf(v[j].z * rinv); o.w = f2bf(v[j].w * rinv);
        *reinterpret_cast<ushort4*>(Tb + (size_t)row * KD + lane * 4 + j * 256) = o;
    }
}

// Prep B: raw bf16 source copy (source norm does not affect per-row ranking)
__global__ void prep_source(const float* __restrict__ S, ushort* __restrict__ Sb) {
    const int wave = threadIdx.x >> 6;
    const int lane = threadIdx.x & 63;
    const int row  = blockIdx.x * 4 + wave;
    const float* p = S + (size_t)row * KD;
#pragma unroll
    for (int j = 0; j < 4; ++j) {
        float4 v = *reinterpret_cast<const float4*>(p + lane * 4 + j * 256);
        ushort4 o;
        o.x = f2bf(v.x); o.y = f2bf(v.y); o.z = f2bf(v.z); o.w = f2bf(v.w);
        *reinterpret_cast<ushort4*>(Sb + (size_t)row * KD + lane * 4 + j * 256) = o;
    }
}

// ---------------------------------------------------------------------------
// Screen: 256x256 bf16 MFMA GEMM + per-lane packed top-8 per source column.
// 512 threads = 8 waves (2 target halves wr x 4 source quarters wc); per wave
// 128 targets x 64 sources = acc[8][4] f32x4, 32 MFMA / 12 ds_read_b128 per
// K-step (1.5x fewer LDS bytes/FLOP than the 128^2/4-wave shape — the R8
// counters put that shape exactly on the 85 B/cy LDS-BW ceiling).
// Pipeline (R7/R8-proven): STAGE(s+1) -> vmcnt(4) -> s_barrier ->
// ds_read frags -> MFMA -> s_barrier. 2 x 32KB buffers (s&1) = 64KB ->
// 2 blocks/CU. Beat-conflict-free swizzle: chunk16 ^= (row>>1)&3.
// ---------------------------------------------------------------------------
__global__ __launch_bounds__(512, 2)
void screen_kernel(const ushort* __restrict__ Sb, const ushort* __restrict__ Tb,
                   uint32_t* __restrict__ cand_out) {
    __shared__ __align__(16) unsigned char lds[2 * BUFSZ];

    const int tid  = threadIdx.x;
    const int lane = tid & 63, wid = tid >> 6;
    const int wr = wid >> 2, wc = wid & 3;
    const int l15 = lane & 15, l4 = lane >> 4;

    const int bx = blockIdx.x;           // source block (fastest)
    const int by = blockIdx.y;           // target slice
    const int sb   = bx * BS;
    const int tgt0 = by * SLICE;

    // staging: one gload16 = 512 threads x 16B = 8KB = 128 rows x 64B.
    // thread t covers row t>>2, physical chunk t&3; pre-swizzled source column
    // (physical chunk p holds logical chunk p ^ ((row>>1)&3); (row>>1)&3 == (t>>3)&3,
    //  invariant under row += 128)
    const int srow = tid >> 2;                           // 0..127
    const int scc  = ((tid & 3) ^ ((tid >> 3) & 3)) * 8; // logical elem offset
    const ushort* aStage = Tb + (size_t)(tgt0 + srow) * KD + scc;
    const ushort* bStage = Sb + (size_t)(sb   + srow) * KD + scc;

    // fragment read: physical chunk = l4 ^ ((row>>1)&3), row ≡ l15 (mod 16)
    const int swz = (l4 ^ ((l15 >> 1) & 3)) * 16;
    int aOff[8], bOff[4];
#pragma unroll
    for (int mg = 0; mg < 8; ++mg) aOff[mg] = (wr * 128 + mg * 16 + l15) * 64 + swz;
#pragma unroll
    for (int ng = 0; ng < 4; ++ng) bOff[ng] = 16384 + (wc * 64 + ng * 16 + l15) * 64 + swz;

#define BARX()  __builtin_amdgcn_s_barrier()
#define FENCE() asm volatile("" ::: "memory")
#define VM4()   asm volatile("s_waitcnt vmcnt(4)" ::: "memory")
#define VM0()   asm volatile("s_waitcnt vmcnt(0)" ::: "memory")

    // STAGE(s): 4 gloads (A rows 0-127, A rows 128-255, B rows 0-127, B 128-255)
#define STAGE(s_) do {                                                         \
        const int tt_ = (s_) >> 5, ks_ = (s_) & 31;                            \
        unsigned char* d_ = lds + (((s_) & 1) ? BUFSZ : 0) + tid * 16;         \
        const ushort* a_ = aStage + (size_t)(tt_ * BT) * KD + ks_ * 32;        \
        const ushort* b_ = bStage + ks_ * 32;                                  \
        gload16(a_,            d_);                                            \
        gload16(a_ + 128 * KD, d_ + 8192);                                     \
        gload16(b_,            d_ + 16384);                                    \
        gload16(b_ + 128 * KD, d_ + 16384 + 8192);                             \
    } while (0)

    uint32_t cand[4][8];
#pragma unroll
    for (int n = 0; n < 4; ++n)
#pragma unroll
        for (int j = 0; j < 8; ++j) cand[n][j] = 0xFF800000u;   // -inf, idx 0

    STAGE(0);

#pragma unroll 1
    for (int tt = 0; tt < NTILE; ++tt) {
        f32x4 acc[8][4];
#pragma unroll
        for (int mg = 0; mg < 8; ++mg)
#pragma unroll
            for (int ng = 0; ng < 4; ++ng) acc[mg][ng] = (f32x4){0.f, 0.f, 0.f, 0.f};

#pragma unroll 1
        for (int ks = 0; ks < TSTEP; ++ks) {
            const int s = tt * TSTEP + ks;
            if (s + 1 < TOTST) { STAGE(s + 1); VM4(); }
            else               { VM0(); }
            BARX(); FENCE();

            const unsigned char* cb = lds + ((s & 1) ? BUFSZ : 0);
            bf16x8 af[8], bf[4];
#pragma unroll
            for (int mg = 0; mg < 8; ++mg)
                af[mg] = *reinterpret_cast<const bf16x8*>(cb + aOff[mg]);
#pragma unroll
            for (int ng = 0; ng < 4; ++ng)
                bf[ng] = *reinterpret_cast<const bf16x8*>(cb + bOff[ng]);
#pragma unroll
            for (int mg = 0; mg < 8; ++mg)
#pragma unroll
                for (int ng = 0; ng < 4; ++ng)
                    acc[mg][ng] = __builtin_amdgcn_mfma_f32_16x16x32_bf16(af[mg], bf[ng], acc[mg][ng], 0, 0, 0);

            FENCE(); BARX();
        }

        // screening scan (registers only; in-flight stage keeps flying)
        // C layout: col=l15 (source), row = l4*4+q (target within fragment)
        const int tb = tgt0 + tt * BT;
#pragma unroll
        for (int n = 0; n < 4; ++n) {
            float c7 = __uint_as_float(cand[n][7]);
#pragma unroll
            for (int mg = 0; mg < 8; ++mg) {
#pragma unroll
                for (int q = 0; q < 4; ++q) {
                    const float v = acc[mg][n][q];
                    if (v > c7) {
                        const int tg = tb + wr * 128 + mg * 16 + l4 * 4 + q;
                        const uint32_t pk = (__float_as_uint(v) & 0xFFFF0000u) | (uint32_t)tg;
                        insert_desc<8>(cand[n], pk);
                        c7 = __uint_as_float(cand[n][7]);
                    }
                }
            }
        }
    }
#undef STAGE

    // ---- candidate merge ----
    // intra-wave: 4 owner lanes per source column (l4=0..3) -> lane l4=0
#pragma unroll
    for (int n = 0; n < 4; ++n) {
#pragma unroll
        for (int off = 32; off >= 16; off >>= 1) {
            uint32_t inc[8];
#pragma unroll
            for (int j = 0; j < 8; ++j)
                inc[j] = (uint32_t)__shfl_down((int)cand[n][j], off);
#pragma unroll
            for (int j = 0; j < 8; ++j)
                if (__uint_as_float(inc[j]) > __uint_as_float(cand[n][7]))
                    insert_desc<8>(cand[n], inc[j]);
        }
    }

    __syncthreads();                     // full drain; LDS reusable
    uint32_t* mbuf = (uint32_t*)lds;     // [256 sources][16 slots] = 16KB
    if (l4 == 0) {
#pragma unroll
        for (int n = 0; n < 4; ++n) {
            const int sc = wc * 64 + n * 16 + l15;
#pragma unroll
            for (int j = 0; j < 8; ++j) mbuf[sc * 16 + wr * 8 + j] = cand[n][j];
        }
    }
    __syncthreads();

    if (tid < BS) {
        uint32_t best[8];
#pragma unroll
        for (int j = 0; j < 8; ++j) best[j] = 0xFF800000u;
        const uint32_t* rowp = mbuf + tid * 16;
#pragma unroll
        for (int c = 0; c < 16; ++c) {
            const uint32_t pk = rowp[c];
            if (__uint_as_float(pk) > __uint_as_float(best[7])) insert_desc<8>(best, pk);
        }
        uint32_t* dst = cand_out + (size_t)(sb + tid) * NCAND + by * 8;
#pragma unroll
        for (int j = 0; j < 8; ++j) dst[j] = best[j];
    }
}

// ---------------------------------------------------------------------------
// Final: per source row, screen-top-16 of NCAND candidates -> fp32 rescore ->
// exact top-4 -> gather + mean. One block (256 threads) per row.
// ---------------------------------------------------------------------------
__global__ __launch_bounds__(256)
void final_kernel(const uint32_t* __restrict__ cand_out, const float* __restrict__ S,
                  const float* __restrict__ T, const float* __restrict__ tinv,
                  float* __restrict__ out) {
    __shared__ uint32_t cl[NCAND];
    __shared__ __align__(16) float srow[KD];
    __shared__ float rv[16];
    __shared__ int   ri[16];
    __shared__ int   sel[4];

    const int r = blockIdx.x;
    const int tid = threadIdx.x;

    cl[tid] = cand_out[(size_t)r * NCAND + tid];
    *reinterpret_cast<float4*>(srow + tid * 4) =
        *reinterpret_cast<const float4*>(S + (size_t)r * KD + tid * 4);
    __syncthreads();

    if (tid == 0) {
        uint32_t best[16];
#pragma unroll
        for (int j = 0; j < 16; ++j) best[j] = 0xFF800000u;
        for (int c = 0; c < NCAND; ++c) {
            const uint32_t pk = cl[c];
            if (__uint_as_float(pk) > __uint_as_float(best[15])) insert_desc<16>(best, pk);
        }
#pragma unroll
        for (int j = 0; j < 16; ++j) ri[j] = (int)(best[j] & 0xFFFFu);
    }
    __syncthreads();

    const int lane = tid & 63, wv = tid >> 6;
    for (int c = wv; c < 16; c += 4) {
        const int idx = ri[c];
        const float* tp = T + (size_t)idx * KD;
        float s = 0.f;
#pragma unroll
        for (int j = 0; j < 4; ++j) {
            const float4 tv = *reinterpret_cast<const float4*>(tp + lane * 4 + j * 256);
            const float4 sv = *reinterpret_cast<const float4*>(srow + lane * 4 + j * 256);
            s += tv.x * sv.x + tv.y * sv.y + tv.z * sv.z + tv.w * sv.w;
        }
#pragma unroll
        for (int off = 32; off; off >>= 1) s += __shfl_xor(s, off);
        if (lane == 0) rv[c] = s * tinv[idx];
    }
    __syncthreads();

    if (tid == 0) {
        float b0 = -INFINITY, b1 = -INFINITY, b2 = -INFINITY, b3 = -INFINITY;
        int s0 = 0, s1 = 0, s2 = 0, s3 = 0;
        for (int c = 0; c < 16; ++c) {
            const float v = rv[c]; const int id = ri[c];
            if (v > b3) {
                if (v > b0)      { b3=b2;s3=s2; b2=b1;s2=s1; b1=b0;s1=s0; b0=v;s0=id; }
                else if (v > b1) { b3=b2;s3=s2; b2=b1;s2=s1; b1=v;s1=id; }
                else if (v > b2) { b3=b2;s3=s2; b2=v;s2=id; }
                else             { b3=v;s3=id; }
            }
        }
        sel[0]=s0; sel[1]=s1; sel[2]=s2; sel[3]=s3;
    }
    __syncthreads();

    float4 a = make_float4(0.f, 0.f, 0.f, 0.f);
#pragma unroll
    for (int q = 0; q < 4; ++q) {
        const float4 v = *reinterpret_cast<const float4*>(T + (size_t)sel[q] * KD + tid * 4);
        a.x += v.x; a.y += v.y; a.z += v.z; a.w += v.w;
    }
    a.x *= 0.25f; a.y *= 0.25f; a.z *= 0.25f; a.w *= 0.25f;
    *reinterpret_cast<float4*>(out + (size_t)r * KD + tid * 4) = a;
}

// ===========================================================================
// Fallback (round-1 proven fp32 path) — used only if ws_size is too small.
// ===========================================================================
#define FNS    32
#define FSLICE (NTGT / FNS)
#define FBM 128
#define FBN 128
#define FBK 16
#define FNTILE (FSLICE / FBN)
#define FLDA 132
#define FLDSS 33

__global__ void tinv_kernel(const float* __restrict__ T, float* __restrict__ tinv) {
    const int wave = threadIdx.x >> 6;
    const int lane = threadIdx.x & 63;
    const int row  = blockIdx.x * 4 + wave;
    const float* p = T + (size_t)row * KD;
    float s = 0.f;
#pragma unroll
    for (int j = 0; j < 4; ++j) {
        float4 v = *reinterpret_cast<const float4*>(p + lane * 4 + j * 256);
        s += v.x * v.x + v.y * v.y + v.z * v.z + v.w * v.w;
    }
#pragma unroll
    for (int off = 32; off; off >>= 1) s += __shfl_xor(s, off);
    if (lane == 0) tinv[row] = 1.0f / sqrtf(fmaxf(s, 1e-24f));
}

__global__ __launch_bounds__(256, 2)
void simtopk_kernel(const float* __restrict__ S, const float* __restrict__ T,
                    const float* __restrict__ tinv,
                    float* __restrict__ pval, int* __restrict__ pidx) {
    __shared__ float smem[2 * FBK * FLDA];
    __shared__ float tinvS[FBN];
    float* As = smem;
    float* Bs = smem + FBK * FLDA;
    float* Ss = smem;

    const int tid = threadIdx.x;
    const int tx = tid & 15, ty = tid >> 4;
    const int rb   = blockIdx.x;
    const int tgt0 = blockIdx.y * FSLICE;
    const size_t abase = (size_t)(rb * FBM) * KD;

    float t0 = -INFINITY, t1 = -INFINITY, t2 = -INFINITY, t3 = -INFINITY;
    int   i0 = 0, i1 = 0, i2 = 0, i3 = 0;

    for (int nt = 0; nt < FNTILE; ++nt) {
        const int tb = tgt0 + nt * FBN;
        float acc[8][8];
#pragma unroll
        for (int i = 0; i < 8; ++i)
#pragma unroll
            for (int j = 0; j < 8; ++j) acc[i][j] = 0.f;

        for (int kk = 0; kk < KD; kk += FBK) {
            const int rr = tid >> 2;
            const int c4 = (tid & 3) * 4;
#pragma unroll
            for (int h = 0; h < 2; ++h) {
                const int row = rr + h * 64;
                float4 av = *reinterpret_cast<const float4*>(S + abase + (size_t)row * KD + kk + c4);
                float4 bv = *reinterpret_cast<const float4*>(T + (size_t)(tb + row) * KD + kk + c4);
                As[(c4 + 0) * FLDA + row] = av.x; As[(c4 + 1) * FLDA + row] = av.y;
                As[(c4 + 2) * FLDA + row] = av.z; As[(c4 + 3) * FLDA + row] = av.w;
                Bs[(c4 + 0) * FLDA + row] = bv.x; Bs[(c4 + 1) * FLDA + row] = bv.y;
                Bs[(c4 + 2) * FLDA + row] = bv.z; Bs[(c4 + 3) * FLDA + row] = bv.w;
            }
            __syncthreads();
#pragma unroll
            for (int k = 0; k < FBK; ++k) {
                float a[8], b[8];
                *reinterpret_cast<float4*>(&a[0]) = *reinterpret_cast<float4*>(&As[k * FLDA + ty * 8]);
                *reinterpret_cast<float4*>(&a[4]) = *reinterpret_cast<float4*>(&As[k * FLDA + ty * 8 + 4]);
                *reinterpret_cast<float4*>(&b[0]) = *reinterpret_cast<float4*>(&Bs[k * FLDA + tx * 4]);
                *reinterpret_cast<float4*>(&b[4]) = *reinterpret_cast<float4*>(&Bs[k * FLDA + 64 + tx * 4]);
#pragma unroll
                for (int i = 0; i < 8; ++i)
#pragma unroll
                    for (int j = 0; j < 8; ++j)
                        acc[i][j] = fmaf(a[i], b[j], acc[i][j]);
            }
            __syncthreads();
        }

        if (tid < FBN) tinvS[tid] = tinv[tb + tid];
        __syncthreads();

#pragma unroll
        for (int cc = 0; cc < 4; ++cc) {
            const int g = cc >> 1;
            if ((tx >> 3) == (cc & 1)) {
                const int txl = tx & 7;
#pragma unroll
                for (int i = 0; i < 8; ++i) {
                    const int rrow = ty * 8 + i;
#pragma unroll
                    for (int j = 0; j < 4; ++j) {
                        const int colc = 4 * txl + j;
                        Ss[rrow * FLDSS + colc] = acc[i][g * 4 + j] * tinvS[cc * 32 + colc];
                    }
                }
            }
            __syncthreads();
            if (tid < FBM) {
#pragma unroll 4
                for (int c = 0; c < 32; ++c) {
                    const float v = Ss[tid * FLDSS + c];
                    if (v > t3) {
                        const int gi = tb + cc * 32 + c;
                        if (v > t0)      { t3=t2;i3=i2; t2=t1;i2=i1; t1=t0;i1=i0; t0=v;i0=gi; }
                        else if (v > t1) { t3=t2;i3=i2; t2=t1;i2=i1; t1=v;i1=gi; }
                        else if (v > t2) { t3=t2;i3=i2; t2=v;i2=gi; }
                        else             { t3=v;i3=gi; }
                    }
                }
            }
            __syncthreads();
        }
    }

    if (tid < FBM) {
        const int row = rb * FBM + tid;
        const size_t base = ((size_t)blockIdx.y * M + row) * 4;
        pval[base + 0] = t0; pval[base + 1] = t1; pval[base + 2] = t2; pval[base + 3] = t3;
        pidx[base + 0] = i0; pidx[base + 1] = i1; pidx[base + 2] = i2; pidx[base + 3] = i3;
    }
}

__global__ void merge_kernel(const float* __restrict__ pval, const int* __restrict__ pidx,
                             const float* __restrict__ T, float* __restrict__ out) {
    __shared__ float cv[FNS * 4];
    __shared__ int   ci[FNS * 4];
    __shared__ int   sel[4];
    const int r = blockIdx.x;
    const int tid = threadIdx.x;

    if (tid < FNS * 4) {
        const int s = tid >> 2, q = tid & 3;
        const size_t base = ((size_t)s * M + r) * 4 + q;
        cv[tid] = pval[base];
        ci[tid] = pidx[base];
    }
    __syncthreads();

    if (tid == 0) {
        float t0 = -INFINITY, t1 = -INFINITY, t2 = -INFINITY, t3 = -INFINITY;
        int   j0 = 0, j1 = 0, j2 = 0, j3 = 0;
        for (int c = 0; c < FNS * 4; ++c) {
            const float v = cv[c];
            if (v > t3) {
                const int gi = ci[c];
                if (v > t0)      { t3=t2;j3=j2; t2=t1;j2=j1; t1=t0;j1=j0; t0=v;j0=gi; }
                else if (v > t1) { t3=t2;j3=j2; t2=t1;j2=j1; t1=v;j1=gi; }
                else if (v > t2) { t3=t2;j3=j2; t2=v;j2=gi; }
                else             { t3=v;j3=gi; }
            }
        }
        sel[0] = j0; sel[1] = j1; sel[2] = j2; sel[3] = j3;
    }
    __syncthreads();

    const int d = tid * 4;
    float4 a = make_float4(0.f, 0.f, 0.f, 0.f);
#pragma unroll
    for (int q = 0; q < 4; ++q) {
        const float4 v = *reinterpret_cast<const float4*>(T + (size_t)sel[q] * KD + d);
        a.x += v.x; a.y += v.y; a.z += v.z; a.w += v.w;
    }
    a.x *= 0.25f; a.y *= 0.25f; a.z *= 0.25f; a.w *= 0.25f;
    *reinterpret_cast<float4*>(out + (size_t)r * KD + d) = a;
}

// ---------------------------------------------------------------------------
extern "C" void kernel_launch(void* const* d_in, const int* in_sizes, int n_in,
                              void* d_out, int out_size, void* d_ws, size_t ws_size,
                              hipStream_t stream) {
    const float* S = (const float*)d_in[0];   // [4096,1024]
    const float* T = (const float*)d_in[1];   // [65536,1024]
    float* out = (float*)d_out;               // [4096,1024]

    const size_t sz_tinv = (size_t)NTGT * 4;                 // 256 KB
    const size_t sz_Sb   = (size_t)M * KD * 2;               // 8 MB
    const size_t sz_Tb   = (size_t)NTGT * KD * 2;            // 128 MB
    const size_t sz_cand = (size_t)M * NCAND * 4;            // 4 MB
    const size_t need = sz_tinv + sz_Sb + sz_Tb + sz_cand;   // ~140.3 MB

    if (ws_size >= need) {
        float*    tinv = (float*)d_ws;
        ushort*   Sb   = (ushort*)((char*)d_ws + sz_tinv);
        ushort*   Tb   = (ushort*)((char*)d_ws + sz_tinv + sz_Sb);
        uint32_t* cand = (uint32_t*)((char*)d_ws + sz_tinv + sz_Sb + sz_Tb);

        prep_targets<<<NTGT / 4, 256, 0, stream>>>(T, tinv, Tb);
        prep_source<<<M / 4, 256, 0, stream>>>(S, Sb);
        screen_kernel<<<dim3(M / BS, NS), 512, 0, stream>>>(Sb, Tb, cand);
        final_kernel<<<M, 256, 0, stream>>>(cand, S, T, tinv, out);
    } else {
        // round-1 fp32 fallback (~7 ms, proven correct)
        float* tinv = (float*)d_ws;
        float* pval = tinv + NTGT;
        int*   pidx = (int*)(pval + (size_t)FNS * M * 4);

        tinv_kernel<<<NTGT / 4, 256, 0, stream>>>(T, tinv);
        simtopk_kernel<<<dim3(M / FBM, FNS), 256, 0, stream>>>(S, T, tinv, pval, pidx);
        merge_kernel<<<M, 256, 0, stream>>>(pval, pidx, T, out);
    }
}